// Round 1
// baseline (413.540 us; speedup 1.0000x reference)
//
#include <hip/hip_runtime.h>

// Problem constants
#define BSZ   32
#define SEQ   4096
#define FDIM  512
#define KTOP  4
#define FK    128                 // FDIM / KTOP
#define MTOT  (BSZ * SEQ)         // 131072 GEMM rows
#define SCHUNKS 16
#define SCH_LEN (SEQ / SCHUNKS)   // 256

typedef __attribute__((ext_vector_type(8))) short bf16x8;
typedef __attribute__((ext_vector_type(4))) float f32x4;
typedef __attribute__((ext_vector_type(8))) unsigned short u16x8;

typedef __attribute__((address_space(1))) void void_g;
typedef __attribute__((address_space(3))) void void_l;

static __device__ __forceinline__ void load_lds16(const void* g, void* l) {
  __builtin_amdgcn_global_load_lds((void_g*)g, (void_l*)l, 16, 0, 0);
}

static __device__ __forceinline__ unsigned short f2bf(float f) {
  unsigned int u = __float_as_uint(f);
  unsigned int r = (u + 0x7fffu + ((u >> 16) & 1u)) >> 16;  // RNE
  return (unsigned short)r;
}
static __device__ __forceinline__ float bf2f(unsigned short b) {
  return __uint_as_float(((unsigned int)b) << 16);
}

// ---------------------------------------------------------------- cvt x -> bf16
__global__ __launch_bounds__(256) void cvt_x_kernel(const float* __restrict__ x,
                                                    unsigned short* __restrict__ xb) {
  const long n = (long)MTOT * FDIM;  // 67108864
  long i0 = ((long)blockIdx.x * blockDim.x + threadIdx.x) * 8;
  long stride = (long)gridDim.x * blockDim.x * 8;
  for (long i = i0; i < n; i += stride) {
    float4 a = *(const float4*)(x + i);
    float4 b = *(const float4*)(x + i + 4);
    u16x8 o;
    o[0] = f2bf(a.x); o[1] = f2bf(a.y); o[2] = f2bf(a.z); o[3] = f2bf(a.w);
    o[4] = f2bf(b.x); o[5] = f2bf(b.y); o[6] = f2bf(b.z); o[7] = f2bf(b.w);
    *(u16x8*)(xb + i) = o;
  }
}

// ------------------------------------------------- Wu [k][n] f32 -> WuT [n][k] bf16
__global__ __launch_bounds__(256) void cvt_wuT_kernel(const float* __restrict__ Wu,
                                                      unsigned short* __restrict__ WuT) {
  int nn = blockIdx.x;  // 0..511
  for (int k = threadIdx.x; k < FDIM; k += blockDim.x)
    WuT[(size_t)nn * FDIM + k] = f2bf(Wu[(size_t)k * FDIM + nn]);
}

// ------------------------------------------------------------------- R precompute
// R[g][q] = sum_m P2[g][m] * Q[(g%4)*128 + m][q],  P2[g][m] = P_flat[g*128+m]
__global__ __launch_bounds__(256) void compute_R_kernel(const float* __restrict__ P,
                                                        const float* __restrict__ Q,
                                                        float* __restrict__ R) {
  int g = blockIdx.y;                        // 0..511
  int q = blockIdx.x * 256 + threadIdx.x;    // 0..511
  __shared__ float p2[FK];
  if (threadIdx.x < FK) p2[threadIdx.x] = P[(size_t)g * FK + threadIdx.x];
  __syncthreads();
  const float* Qb = Q + (size_t)((g & 3) * FK) * FDIM + q;
  float s = 0.f;
#pragma unroll 8
  for (int m = 0; m < FK; ++m) s = fmaf(p2[m], Qb[(size_t)m * FDIM], s);
  R[(size_t)g * FDIM + q] = s;
}

// ------------------------------------------------------------ GEMM: Ux = relu(x@Wu)
// A [MTOT][512] bf16, Bt [n][k] bf16 (Wu transposed), C [MTOT][512] bf16.
#define BM 128
#define BN 128
#define BKS 64

__global__ __launch_bounds__(256) void gemm_relu_kernel(
    const unsigned short* __restrict__ A, const unsigned short* __restrict__ Bt,
    unsigned short* __restrict__ C) {
  __shared__ __align__(16) unsigned short As[BM * BKS];  // [128][64]
  __shared__ __align__(16) unsigned short Bs[BN * BKS];  // [128][64]

  const int tid = threadIdx.x;
  const int lane = tid & 63;
  const int w = tid >> 6;                 // 4 waves, 2x2
  const int wm = w & 1, wn = w >> 1;
  const int mt = blockIdx.x >> 2;         // 1024 m-tiles
  const int nt = blockIdx.x & 3;          // 4 n-tiles
  const int m0 = mt * BM, n0 = nt * BN;

  const int lr = lane & 15;               // M-row / N-col within 16
  const int lk = (lane >> 4) << 3;        // k offset within 32
  const int seg_r = lane >> 3;            // staging: row-in-segment 0..7
  const int seg_c = (lane & 7) << 3;      // staging: col 0,8,..,56

  f32x4 acc[4][4];
#pragma unroll
  for (int mi = 0; mi < 4; ++mi)
#pragma unroll
    for (int ni = 0; ni < 4; ++ni) acc[mi][ni] = {0.f, 0.f, 0.f, 0.f};

  for (int kt = 0; kt < FDIM / BKS; ++kt) {
    __syncthreads();  // previous iter's LDS reads done
#pragma unroll
    for (int i = 0; i < 4; ++i) {
      int seg = w * 4 + i;                // 16 segments of 8 rows x 64 cols
      int row = seg * 8 + seg_r;
      load_lds16(A + (size_t)(m0 + row) * FDIM + kt * BKS + seg_c, As + seg * 512);
      load_lds16(Bt + (size_t)(n0 + row) * FDIM + kt * BKS + seg_c, Bs + seg * 512);
    }
    __syncthreads();  // staged (compiler drains vmcnt before barrier)

#pragma unroll
    for (int kk = 0; kk < 2; ++kk) {
      bf16x8 af[4], bfr[4];
#pragma unroll
      for (int mi = 0; mi < 4; ++mi)
        af[mi] = *(const bf16x8*)(As + (wm * 64 + mi * 16 + lr) * BKS + kk * 32 + lk);
#pragma unroll
      for (int ni = 0; ni < 4; ++ni)
        bfr[ni] = *(const bf16x8*)(Bs + (wn * 64 + ni * 16 + lr) * BKS + kk * 32 + lk);
#pragma unroll
      for (int mi = 0; mi < 4; ++mi)
#pragma unroll
        for (int ni = 0; ni < 4; ++ni)
          acc[mi][ni] = __builtin_amdgcn_mfma_f32_16x16x32_bf16(af[mi], bfr[ni],
                                                                acc[mi][ni], 0, 0, 0);
    }
  }

  // epilogue: relu + bf16 store.  D: col = lane&15, row = (lane>>4)*4 + r
  const int r0 = (lane >> 4) * 4;
#pragma unroll
  for (int mi = 0; mi < 4; ++mi)
#pragma unroll
    for (int ni = 0; ni < 4; ++ni)
#pragma unroll
      for (int r = 0; r < 4; ++r) {
        int row = m0 + wm * 64 + mi * 16 + r0 + r;
        int col = n0 + wn * 64 + ni * 16 + (lane & 15);
        float v = acc[mi][ni][r];
        v = v > 0.f ? v : 0.f;
        C[(size_t)row * FDIM + col] = f2bf(v);
      }
}

// --------------------------------------------------- per-s-chunk top-4 per column
// cand layout: [(b*512 + f) * 16 + sc] * 4 + j   (descending within each 4)
__global__ __launch_bounds__(256) void topk_partial_kernel(
    const unsigned short* __restrict__ Ux, float* __restrict__ cand) {
  const int sc = blockIdx.x;   // 0..15
  const int b = blockIdx.y;    // 0..31
  const int f0 = threadIdx.x * 2;
  const unsigned short* base = Ux + (size_t)(b * SEQ + sc * SCH_LEN) * FDIM + f0;
  float a0 = -1e30f, a1 = -1e30f, a2 = -1e30f, a3 = -1e30f;
  float c0 = -1e30f, c1 = -1e30f, c2 = -1e30f, c3 = -1e30f;
  for (int s = 0; s < SCH_LEN; ++s) {
    unsigned int ld = *(const unsigned int*)(base + (size_t)s * FDIM);
    float v0 = bf2f((unsigned short)(ld & 0xffffu));
    float v1 = bf2f((unsigned short)(ld >> 16));
    if (v0 > a3) {
      if (v0 > a0)      { a3 = a2; a2 = a1; a1 = a0; a0 = v0; }
      else if (v0 > a1) { a3 = a2; a2 = a1; a1 = v0; }
      else if (v0 > a2) { a3 = a2; a2 = v0; }
      else              { a3 = v0; }
    }
    if (v1 > c3) {
      if (v1 > c0)      { c3 = c2; c2 = c1; c1 = c0; c0 = v1; }
      else if (v1 > c1) { c3 = c2; c2 = c1; c1 = v1; }
      else if (v1 > c2) { c3 = c2; c2 = v1; }
      else              { c3 = v1; }
    }
  }
  float* cb0 = cand + ((size_t)(b * FDIM + f0) * SCHUNKS + sc) * 4;
  cb0[0] = a0; cb0[1] = a1; cb0[2] = a2; cb0[3] = a3;
  float* cb1 = cand + ((size_t)(b * FDIM + f0 + 1) * SCHUNKS + sc) * 4;
  cb1[0] = c0; cb1[1] = c1; cb1[2] = c2; cb1[3] = c3;
}

// ------------------------------------- merge candidates + 4-term contraction + relu
__global__ __launch_bounds__(256) void epilogue_kernel(
    const float* __restrict__ cand, const float* __restrict__ R,
    const float* __restrict__ Bb, float* __restrict__ out) {
  const int bf = blockIdx.x;         // 0..16383
  const int b = bf >> 9, ff = bf & 511;
  const int m2 = ff & 127;
  __shared__ float cv[SCHUNKS * 4];
  __shared__ float tvs[4];
  if (threadIdx.x < SCHUNKS * 4)
    cv[threadIdx.x] = cand[(size_t)(b * FDIM + ff) * (SCHUNKS * 4) + threadIdx.x];
  __syncthreads();
  if (threadIdx.x == 0) {
    float t0 = -1e30f, t1 = -1e30f, t2 = -1e30f, t3 = -1e30f;
    for (int i = 0; i < SCHUNKS * 4; ++i) {
      float v = cv[i];
      if (v > t3) {
        if (v > t0)      { t3 = t2; t2 = t1; t1 = t0; t0 = v; }
        else if (v > t1) { t3 = t2; t2 = t1; t1 = v; }
        else if (v > t2) { t3 = t2; t2 = v; }
        else             { t3 = v; }
      }
    }
    tvs[0] = t0; tvs[1] = t1; tvs[2] = t2; tvs[3] = t3;
  }
  __syncthreads();
  const float t0 = tvs[0], t1 = tvs[1], t2 = tvs[2], t3 = tvs[3];
  const float* R0 = R + (size_t)(4 * m2) * FDIM;
  const float* Bbr = Bb + (size_t)m2 * FDIM;
  float* ob = out + (size_t)(b * FDIM + ff) * FDIM;
  for (int q = threadIdx.x; q < FDIM; q += blockDim.x) {
    float s = Bbr[q];
    s = fmaf(t0, R0[q], s);
    s = fmaf(t1, R0[FDIM + q], s);
    s = fmaf(t2, R0[2 * FDIM + q], s);
    s = fmaf(t3, R0[3 * FDIM + q], s);
    ob[q] = s > 0.f ? s : 0.f;
  }
}

// ---------------------------------------------------------------------------------
extern "C" void kernel_launch(void* const* d_in, const int* in_sizes, int n_in,
                              void* d_out, int out_size, void* d_ws, size_t ws_size,
                              hipStream_t stream) {
  const float* x  = (const float*)d_in[0];
  const float* Wu = (const float*)d_in[1];
  const float* P  = (const float*)d_in[2];
  const float* Q  = (const float*)d_in[3];
  const float* Bb = (const float*)d_in[4];
  float* out = (float*)d_out;

  char* ws = (char*)d_ws;
  // workspace layout (total ~274.2 MB)
  unsigned short* xb  = (unsigned short*)(ws);                  // 134217728 B
  unsigned short* ux  = (unsigned short*)(ws + 134217728L);     // 134217728 B
  unsigned short* wuT = (unsigned short*)(ws + 268435456L);     //    524288 B
  float*          R   = (float*)(ws + 268959744L);              //   1048576 B
  float*          cand= (float*)(ws + 270008320L);              //   4194304 B

  hipLaunchKernelGGL(cvt_x_kernel, dim3(2048), dim3(256), 0, stream, x, xb);
  hipLaunchKernelGGL(cvt_wuT_kernel, dim3(512), dim3(256), 0, stream, Wu, wuT);
  hipLaunchKernelGGL(compute_R_kernel, dim3(2, 512), dim3(256), 0, stream, P, Q, R);
  hipLaunchKernelGGL(gemm_relu_kernel, dim3(4096), dim3(256), 0, stream, xb, wuT, ux);
  hipLaunchKernelGGL(topk_partial_kernel, dim3(SCHUNKS, BSZ), dim3(256), 0, stream, ux, cand);
  hipLaunchKernelGGL(epilogue_kernel, dim3(BSZ * FDIM), dim3(256), 0, stream, cand, R, Bb, out);
}

// Round 2
// 234.842 us; speedup vs baseline: 1.7609x; 1.7609x over previous
//
#include <hip/hip_runtime.h>

// Problem constants
#define BSZ   32
#define SEQ   4096
#define FDIM  512
#define KTOP  4
#define FK    128                 // FDIM / KTOP
#define MTOT  (BSZ * SEQ)         // 131072 GEMM rows
#define NCHUNK 32                 // 4096 / 128 seq-chunks per batch

typedef __attribute__((ext_vector_type(8))) short bf16x8;
typedef __attribute__((ext_vector_type(4))) float f32x4;
typedef __attribute__((ext_vector_type(8))) unsigned short u16x8;

typedef __attribute__((address_space(1))) void void_g;
typedef __attribute__((address_space(3))) void void_l;

static __device__ __forceinline__ void load_lds16(const void* g, void* l) {
  __builtin_amdgcn_global_load_lds((void_g*)g, (void_l*)l, 16, 0, 0);
}

static __device__ __forceinline__ unsigned short f2bf(float f) {
  unsigned int u = __float_as_uint(f);
  unsigned int r = (u + 0x7fffu + ((u >> 16) & 1u)) >> 16;  // RNE
  return (unsigned short)r;
}

// ---- sorting-network helpers (descending) ----
static __device__ __forceinline__ void sort2(float& a, float& b) {
  float mx = fmaxf(a, b), mn = fminf(a, b); a = mx; b = mn;
}
static __device__ __forceinline__ void sort4(float& a, float& b, float& c, float& d) {
  sort2(a, b); sort2(c, d); sort2(a, c); sort2(b, d); sort2(b, c);
}
// merge two descending sorted-4 lists, keep top-4 descending in a..d
static __device__ __forceinline__ void merge4(float& a, float& b, float& c, float& d,
                                              float e, float f, float g, float h) {
  float m0 = fmaxf(a, h), m1 = fmaxf(b, g), m2 = fmaxf(c, f), m3 = fmaxf(d, e);
  sort2(m0, m2); sort2(m1, m3); sort2(m0, m1); sort2(m2, m3);
  a = m0; b = m1; c = m2; d = m3;
}

// ---------------------------------------------------------------- cvt x -> bf16
__global__ __launch_bounds__(256) void cvt_x_kernel(const float* __restrict__ x,
                                                    unsigned short* __restrict__ xb) {
  const long n = (long)MTOT * FDIM;  // 67108864
  long i0 = ((long)blockIdx.x * blockDim.x + threadIdx.x) * 8;
  long stride = (long)gridDim.x * blockDim.x * 8;
  for (long i = i0; i < n; i += stride) {
    float4 a = *(const float4*)(x + i);
    float4 b = *(const float4*)(x + i + 4);
    u16x8 o;
    o[0] = f2bf(a.x); o[1] = f2bf(a.y); o[2] = f2bf(a.z); o[3] = f2bf(a.w);
    o[4] = f2bf(b.x); o[5] = f2bf(b.y); o[6] = f2bf(b.z); o[7] = f2bf(b.w);
    *(u16x8*)(xb + i) = o;
  }
}

// ------------------------------------------------- Wu [k][n] f32 -> WuT [n][k] bf16
__global__ __launch_bounds__(256) void cvt_wuT_kernel(const float* __restrict__ Wu,
                                                      unsigned short* __restrict__ WuT) {
  int nn = blockIdx.x;  // 0..511
  for (int k = threadIdx.x; k < FDIM; k += blockDim.x)
    WuT[(size_t)nn * FDIM + k] = f2bf(Wu[(size_t)k * FDIM + nn]);
}

// ------------------------------------------------------------------- R precompute
// R[g][q] = sum_m P2[g][m] * Q[(g%4)*128 + m][q],  P2 = P.reshape(512,128)
__global__ __launch_bounds__(256) void compute_R_kernel(const float* __restrict__ P,
                                                        const float* __restrict__ Q,
                                                        float* __restrict__ R) {
  int g = blockIdx.y;                        // 0..511
  int q = blockIdx.x * 256 + threadIdx.x;    // 0..511
  __shared__ float p2[FK];
  if (threadIdx.x < FK) p2[threadIdx.x] = P[(size_t)g * FK + threadIdx.x];
  __syncthreads();
  const float* Qb = Q + (size_t)((g & 3) * FK) * FDIM + q;
  float s = 0.f;
#pragma unroll 8
  for (int m = 0; m < FK; ++m) s = fmaf(p2[m], Qb[(size_t)m * FDIM], s);
  R[(size_t)g * FDIM + q] = s;
}

// --------------------------------- GEMM + fused per-chunk top-4 over 128 seq rows
// A [MTOT][512] bf16, Bt [n][k] bf16. Output: cand[b][f][chunk][4] f32 (sorted desc)
#define BM 128
#define BN 128
#define BKS 64

__global__ __launch_bounds__(256) void gemm_topk_kernel(
    const unsigned short* __restrict__ A, const unsigned short* __restrict__ Bt,
    float* __restrict__ cand) {
  __shared__ __align__(16) unsigned short As[2][BM * BKS];  // 2 x 16 KB
  __shared__ __align__(16) unsigned short Bs[2][BM * BKS];  // 2 x 16 KB
  __shared__ float4 tl[BN * 2];                             // [col][wm] 4 KB

  const int tid = threadIdx.x;
  const int lane = tid & 63;
  const int w = tid >> 6;                 // 4 waves, 2x2
  const int wm = w & 1, wn = w >> 1;

  // XCD-grouped mapping: 4 n-tiles of one m-tile land consecutively on one XCD
  const int xcd = blockIdx.x & 7;
  const int j = blockIdx.x >> 3;
  const int t = xcd * 512 + j;            // 4096 tiles
  const int mt = t >> 2;                  // 1024 m-tiles
  const int nt = t & 3;                   // 4 n-tiles
  const int m0 = mt * BM, n0 = nt * BN;

  const int lr = lane & 15;               // M-row / N-col within 16
  const int lk = (lane >> 4) << 3;        // k offset within 32
  const int seg_r = lane >> 3;            // staging: row-in-segment 0..7
  const int seg_c = (lane & 7) << 3;      // staging: col 0,8,..,56

  f32x4 acc[4][4];
#pragma unroll
  for (int mi = 0; mi < 4; ++mi)
#pragma unroll
    for (int ni = 0; ni < 4; ++ni) acc[mi][ni] = {0.f, 0.f, 0.f, 0.f};

#define STAGE(kt, buf)                                                              \
  {                                                                                 \
    _Pragma("unroll") for (int i = 0; i < 4; ++i) {                                 \
      int seg = w * 4 + i;                                                          \
      int row = seg * 8 + seg_r;                                                    \
      load_lds16(A + (size_t)(m0 + row) * FDIM + (kt) * BKS + seg_c,                \
                 &As[buf][seg * 512]);                                              \
      load_lds16(Bt + (size_t)(n0 + row) * FDIM + (kt) * BKS + seg_c,               \
                 &Bs[buf][seg * 512]);                                              \
    }                                                                               \
  }

  STAGE(0, 0);
  __syncthreads();

  for (int kt = 0; kt < FDIM / BKS; ++kt) {
    const int cur = kt & 1;
    if (kt < FDIM / BKS - 1) STAGE(kt + 1, cur ^ 1);
#pragma unroll
    for (int kk = 0; kk < 2; ++kk) {
      bf16x8 af[4], bfr[4];
#pragma unroll
      for (int mi = 0; mi < 4; ++mi)
        af[mi] = *(const bf16x8*)(&As[cur][(wm * 64 + mi * 16 + lr) * BKS + kk * 32 + lk]);
#pragma unroll
      for (int ni = 0; ni < 4; ++ni)
        bfr[ni] = *(const bf16x8*)(&Bs[cur][(wn * 64 + ni * 16 + lr) * BKS + kk * 32 + lk]);
#pragma unroll
      for (int mi = 0; mi < 4; ++mi)
#pragma unroll
        for (int ni = 0; ni < 4; ++ni)
          acc[mi][ni] = __builtin_amdgcn_mfma_f32_16x16x32_bf16(af[mi], bfr[ni],
                                                                acc[mi][ni], 0, 0, 0);
    }
    __syncthreads();  // drains vmcnt (stage done) + lgkm (reads done)
  }

  // ---- fused top-4 per column over this tile's 128 rows ----
  // D frag: col = n0 + wn*64 + ni*16 + (lane&15); row covers wm*64 + 0..63 via
  // mi(4) x r(4) x lane>>4(4); reduce rows in-lane, then shfl over lane>>4.
#pragma unroll
  for (int ni = 0; ni < 4; ++ni) {
    float a0 = acc[0][ni][0], a1 = acc[0][ni][1], a2 = acc[0][ni][2], a3 = acc[0][ni][3];
    sort4(a0, a1, a2, a3);
    {
      float b0 = acc[1][ni][0], b1 = acc[1][ni][1], b2 = acc[1][ni][2], b3 = acc[1][ni][3];
      sort4(b0, b1, b2, b3);
      merge4(a0, a1, a2, a3, b0, b1, b2, b3);
    }
    {
      float c0 = acc[2][ni][0], c1 = acc[2][ni][1], c2 = acc[2][ni][2], c3 = acc[2][ni][3];
      sort4(c0, c1, c2, c3);
      float d0 = acc[3][ni][0], d1 = acc[3][ni][1], d2 = acc[3][ni][2], d3 = acc[3][ni][3];
      sort4(d0, d1, d2, d3);
      merge4(c0, c1, c2, c3, d0, d1, d2, d3);
      merge4(a0, a1, a2, a3, c0, c1, c2, c3);
    }
#pragma unroll
    for (int off = 16; off < 64; off <<= 1) {
      float e0 = __shfl_xor(a0, off), e1 = __shfl_xor(a1, off);
      float e2 = __shfl_xor(a2, off), e3 = __shfl_xor(a3, off);
      merge4(a0, a1, a2, a3, e0, e1, e2, e3);
    }
    if (lane < 16) {
      float4 v; v.x = a0; v.y = a1; v.z = a2; v.w = a3;
      tl[(wn * 64 + ni * 16 + lane) * 2 + wm] = v;
    }
  }
  __syncthreads();

  if (tid < BN) {
    const int col = tid;
    float4 u = tl[col * 2 + 0];
    float4 v = tl[col * 2 + 1];
    merge4(u.x, u.y, u.z, u.w, v.x, v.y, v.z, v.w);
    const int b = mt >> 5;          // 32 m-tiles per batch
    const int chunk = mt & 31;
    const int f = n0 + col;
    float4* cb = (float4*)(cand + (((size_t)(b * FDIM + f)) * NCHUNK + chunk) * 4);
    *cb = u;
  }
}

// ---------------------- merge 32 chunk-lists + 4-term contraction + relu -> out
// one wave per output row (b,ff); 4 rows per block
__global__ __launch_bounds__(256) void out_kernel(
    const float* __restrict__ cand, const float* __restrict__ R,
    const float* __restrict__ Bb, float* __restrict__ out) {
  const int row = blockIdx.x * 4 + (threadIdx.x >> 6);  // b*512 + ff
  const int lane = threadIdx.x & 63;
  const int b = row >> 9, ff = row & 511;
  const int m2 = ff & 127;

  // each lane loads one sorted chunk-list (lanes 32..63 duplicate chunks 0..31,
  // which reduce to the same answer)
  const float4 cv = *(const float4*)(cand +
      (((size_t)(b * FDIM + ff)) * NCHUNK + (lane & 31)) * 4);
  float t0 = cv.x, t1 = cv.y, t2 = cv.z, t3 = cv.w;
#pragma unroll
  for (int off = 1; off < 32; off <<= 1) {
    float e0 = __shfl_xor(t0, off), e1 = __shfl_xor(t1, off);
    float e2 = __shfl_xor(t2, off), e3 = __shfl_xor(t3, off);
    merge4(t0, t1, t2, t3, e0, e1, e2, e3);
  }
  t0 = fmaxf(t0, 0.f); t1 = fmaxf(t1, 0.f); t2 = fmaxf(t2, 0.f); t3 = fmaxf(t3, 0.f);

  const float* R0 = R + (size_t)(4 * m2) * FDIM;
  const float* Bbr = Bb + (size_t)m2 * FDIM;
  float* ob = out + (size_t)row * FDIM;
#pragma unroll
  for (int jq = 0; jq < 8; ++jq) {
    const int q = jq * 64 + lane;
    float s = Bbr[q];
    s = fmaf(t0, R0[q], s);
    s = fmaf(t1, R0[FDIM + q], s);
    s = fmaf(t2, R0[2 * FDIM + q], s);
    s = fmaf(t3, R0[3 * FDIM + q], s);
    ob[q] = s > 0.f ? s : 0.f;
  }
}

// ---------------------------------------------------------------------------------
extern "C" void kernel_launch(void* const* d_in, const int* in_sizes, int n_in,
                              void* d_out, int out_size, void* d_ws, size_t ws_size,
                              hipStream_t stream) {
  const float* x  = (const float*)d_in[0];
  const float* Wu = (const float*)d_in[1];
  const float* P  = (const float*)d_in[2];
  const float* Q  = (const float*)d_in[3];
  const float* Bb = (const float*)d_in[4];
  float* out = (float*)d_out;

  char* ws = (char*)d_ws;
  unsigned short* xb  = (unsigned short*)(ws);               // 134217728 B
  unsigned short* wuT = (unsigned short*)(ws + 134217728L);  //    524288 B
  float*          R   = (float*)(ws + 134742016L);           //   1048576 B
  float*          cand= (float*)(ws + 135790592L);           //  33554432 B

  hipLaunchKernelGGL(cvt_x_kernel, dim3(2048), dim3(256), 0, stream, x, xb);
  hipLaunchKernelGGL(cvt_wuT_kernel, dim3(512), dim3(256), 0, stream, Wu, wuT);
  hipLaunchKernelGGL(compute_R_kernel, dim3(2, 512), dim3(256), 0, stream, P, Q, R);
  hipLaunchKernelGGL(gemm_topk_kernel, dim3(4096), dim3(256), 0, stream, xb, wuT, cand);
  hipLaunchKernelGGL(out_kernel, dim3(BSZ * FDIM / 4), dim3(256), 0, stream, cand, R, Bb, out);
}

// Round 3
// 180.459 us; speedup vs baseline: 2.2916x; 1.3014x over previous
//
#include <hip/hip_runtime.h>

// Problem constants
#define BSZ   32
#define SEQ   4096
#define FDIM  512
#define KTOP  4
#define FK    128                 // FDIM / KTOP
#define MTOT  (BSZ * SEQ)         // 131072 GEMM rows
#define NCHUNK 32                 // 4096 / 128 seq-chunks per batch

// 256x256 GEMM tile geometry
#define BM2  256
#define BN2  256
#define BK2  64
#define NKT  (FDIM / BK2)         // 8 K-tiles

typedef __attribute__((ext_vector_type(8))) short bf16x8;
typedef __attribute__((ext_vector_type(4))) float f32x4;
typedef __attribute__((ext_vector_type(8))) unsigned short u16x8;

typedef __attribute__((address_space(1))) void void_g;
typedef __attribute__((address_space(3))) void void_l;

static __device__ __forceinline__ void load_lds16(const void* g, void* l) {
  __builtin_amdgcn_global_load_lds((void_g*)g, (void_l*)l, 16, 0, 0);
}

static __device__ __forceinline__ unsigned short f2bf(float f) {
  unsigned int u = __float_as_uint(f);
  unsigned int r = (u + 0x7fffu + ((u >> 16) & 1u)) >> 16;  // RNE
  return (unsigned short)r;
}

// ---- sorting-network helpers (descending) ----
static __device__ __forceinline__ void sort2(float& a, float& b) {
  float mx = fmaxf(a, b), mn = fminf(a, b); a = mx; b = mn;
}
static __device__ __forceinline__ void sort4(float& a, float& b, float& c, float& d) {
  sort2(a, b); sort2(c, d); sort2(a, c); sort2(b, d); sort2(b, c);
}
// merge two descending sorted-4 lists, keep top-4 descending in a..d
static __device__ __forceinline__ void merge4(float& a, float& b, float& c, float& d,
                                              float e, float f, float g, float h) {
  float m0 = fmaxf(a, h), m1 = fmaxf(b, g), m2 = fmaxf(c, f), m3 = fmaxf(d, e);
  sort2(m0, m2); sort2(m1, m3); sort2(m0, m1); sort2(m2, m3);
  a = m0; b = m1; c = m2; d = m3;
}

// ---------------------------------------------------------------- cvt x -> bf16
__global__ __launch_bounds__(256) void cvt_x_kernel(const float* __restrict__ x,
                                                    unsigned short* __restrict__ xb) {
  const long n = (long)MTOT * FDIM;  // 67108864
  long i0 = ((long)blockIdx.x * blockDim.x + threadIdx.x) * 8;
  long stride = (long)gridDim.x * blockDim.x * 8;
  for (long i = i0; i < n; i += stride) {
    float4 a = *(const float4*)(x + i);
    float4 b = *(const float4*)(x + i + 4);
    u16x8 o;
    o[0] = f2bf(a.x); o[1] = f2bf(a.y); o[2] = f2bf(a.z); o[3] = f2bf(a.w);
    o[4] = f2bf(b.x); o[5] = f2bf(b.y); o[6] = f2bf(b.z); o[7] = f2bf(b.w);
    *(u16x8*)(xb + i) = o;
  }
}

// ------------------------------------------------- Wu [k][n] f32 -> WuT [n][k] bf16
__global__ __launch_bounds__(256) void cvt_wuT_kernel(const float* __restrict__ Wu,
                                                      unsigned short* __restrict__ WuT) {
  int nn = blockIdx.x;  // 0..511
  for (int k = threadIdx.x; k < FDIM; k += blockDim.x)
    WuT[(size_t)nn * FDIM + k] = f2bf(Wu[(size_t)k * FDIM + nn]);
}

// ------------------------------------------------------------------- R precompute
// R[g][q] = sum_m P2[g][m] * Q[(g%4)*128 + m][q],  P2 = P.reshape(512,128)
__global__ __launch_bounds__(256) void compute_R_kernel(const float* __restrict__ P,
                                                        const float* __restrict__ Q,
                                                        float* __restrict__ R) {
  int g = blockIdx.y;                        // 0..511
  int q = blockIdx.x * 256 + threadIdx.x;    // 0..511
  __shared__ float p2[FK];
  if (threadIdx.x < FK) p2[threadIdx.x] = P[(size_t)g * FK + threadIdx.x];
  __syncthreads();
  const float* Qb = Q + (size_t)((g & 3) * FK) * FDIM + q;
  float s = 0.f;
#pragma unroll 8
  for (int m = 0; m < FK; ++m) s = fmaf(p2[m], Qb[(size_t)m * FDIM], s);
  R[(size_t)g * FDIM + q] = s;
}

// ---------------- 256x256 pipelined GEMM + fused per-128-row-chunk top-4
// A [MTOT][512] bf16, Bt [n][k] bf16. Output: cand[b][f][chunk][4] f32 (sorted desc)
// 8 waves (2M x 4N), per-wave output 128x64. Double-buffered LDS, counted vmcnt,
// T2 XOR-swizzle (linear gload_lds dest + inverse-swizzled global source).
__global__ __launch_bounds__(512, 2) void gemm_topk_kernel(
    const unsigned short* __restrict__ A, const unsigned short* __restrict__ Bt,
    float* __restrict__ cand) {
  __shared__ __align__(16) unsigned short As[2][BM2 * BK2];  // 2 x 32 KB
  __shared__ __align__(16) unsigned short Bs[2][BM2 * BK2];  // 2 x 32 KB

  const int tid = threadIdx.x;
  const int lane = tid & 63;
  const int w = tid >> 6;                 // 0..7
  const int wm = w & 1, wn = w >> 1;      // 2 x 4 wave grid

  // XCD-grouped mapping: both n-tiles of one m-tile land adjacent on one XCD.
  const int xcd = blockIdx.x & 7;
  const int jj = blockIdx.x >> 3;         // 0..127
  const int t = xcd * 128 + jj;           // 0..1023
  const int mtile = t >> 1, ntile = t & 1;
  const int m0 = mtile * BM2, n0 = ntile * BN2;

  // ---- staging addressing: 4 gload_lds per operand per K-tile per thread ----
  // linear LDS byte o = i*8192 + tid*16 within the 32KB operand tile;
  // row = o>>7; source colbyte = (o&127) ^ ((row&7)<<4)   [inverse swizzle]
  const char* asrc[4];
  const char* bsrc[4];
#pragma unroll
  for (int i = 0; i < 4; ++i) {
    int o = i * 8192 + tid * 16;
    int row = o >> 7;
    int colb = (o & 127) ^ ((row & 7) << 4);
    asrc[i] = (const char*)(A + (size_t)(m0 + row) * FDIM) + colb;
    bsrc[i] = (const char*)(Bt + (size_t)(n0 + row) * FDIM) + colb;
  }
  const int ldst = (tid >> 6) * 512;      // + i*4096 shorts, wave-uniform base

#define STAGE2(kt, buf)                                                        \
  {                                                                            \
    _Pragma("unroll") for (int i = 0; i < 4; ++i) {                            \
      load_lds16(asrc[i] + (kt) * 128, (void*)(&As[buf][i * 4096 + ldst]));    \
      load_lds16(bsrc[i] + (kt) * 128, (void*)(&Bs[buf][i * 4096 + ldst]));    \
    }                                                                          \
  }

  // ---- fragment read offsets (swizzled) ----
  const int lr = lane & 15;
  const int g16 = lane >> 4;              // 0..3
  const int swz = (lr & 7) << 4;
  // A frag (mi,kk): row = wm*128 + mi*16 + lr  (row&7 == lr&7)
  // byte = row*128 + ((kk*64 + g16*16) ^ swz)
  const int arow0 = (wm * 128 + lr) * 128;
  const int brow0 = (wn * 64 + lr) * 128;

  f32x4 acc[8][4];
#pragma unroll
  for (int mi = 0; mi < 8; ++mi)
#pragma unroll
    for (int ni = 0; ni < 4; ++ni) acc[mi][ni] = {0.f, 0.f, 0.f, 0.f};

  STAGE2(0, 0);

  for (int kt = 0; kt < NKT; ++kt) {
    const int cur = kt & 1;
    if (kt + 1 < NKT) {
      STAGE2(kt + 1, cur ^ 1);
      asm volatile("s_waitcnt vmcnt(8)" ::: "memory");  // own tile-kt loads landed
    } else {
      asm volatile("s_waitcnt vmcnt(0)" ::: "memory");
    }
    __builtin_amdgcn_s_barrier();        // all waves' tile-kt loads landed

    const char* Ab = (const char*)As[cur];
    const char* Bb = (const char*)Bs[cur];
#pragma unroll
    for (int kk = 0; kk < 2; ++kk) {
      bf16x8 af[8], bfr[4];
      const int kcol = kk * 64;
#pragma unroll
      for (int mi = 0; mi < 8; ++mi)
        af[mi] = *(const bf16x8*)(Ab + arow0 + mi * 2048 + ((kcol + g16 * 16) ^ swz));
#pragma unroll
      for (int ni = 0; ni < 4; ++ni)
        bfr[ni] = *(const bf16x8*)(Bb + brow0 + ni * 2048 + ((kcol + g16 * 16) ^ swz));
      __builtin_amdgcn_s_setprio(1);
#pragma unroll
      for (int mi = 0; mi < 8; ++mi)
#pragma unroll
        for (int ni = 0; ni < 4; ++ni)
          acc[mi][ni] = __builtin_amdgcn_mfma_f32_16x16x32_bf16(af[mi], bfr[ni],
                                                                acc[mi][ni], 0, 0, 0);
      __builtin_amdgcn_s_setprio(0);
    }
    __builtin_amdgcn_s_barrier();        // all waves done reading buf[cur]
  }

  // ---- fused top-4: each wave owns one 128-row chunk (wm), cols wn*64..+63 ----
  // D frag: row = wm*128 + mi*16 + g16*4 + r, col = n0 + wn*64 + ni*16 + (lane&15)
  const int mchunk = mtile * 2 + wm;      // global 128-row chunk id
  const int b = mchunk >> 5;
  const int chunk = mchunk & 31;
#pragma unroll
  for (int ni = 0; ni < 4; ++ni) {
    float a0 = acc[0][ni][0], a1 = acc[0][ni][1], a2 = acc[0][ni][2], a3 = acc[0][ni][3];
    sort4(a0, a1, a2, a3);
#pragma unroll
    for (int mi = 1; mi < 8; ++mi) {
      float b0 = acc[mi][ni][0], b1 = acc[mi][ni][1];
      float b2 = acc[mi][ni][2], b3 = acc[mi][ni][3];
      sort4(b0, b1, b2, b3);
      merge4(a0, a1, a2, a3, b0, b1, b2, b3);
    }
#pragma unroll
    for (int off = 16; off < 64; off <<= 1) {
      float e0 = __shfl_xor(a0, off), e1 = __shfl_xor(a1, off);
      float e2 = __shfl_xor(a2, off), e3 = __shfl_xor(a3, off);
      merge4(a0, a1, a2, a3, e0, e1, e2, e3);
    }
    if (lane < 16) {
      const int f = n0 + wn * 64 + ni * 16 + lane;
      float4 v; v.x = a0; v.y = a1; v.z = a2; v.w = a3;
      *(float4*)(cand + (((size_t)(b * FDIM + f)) * NCHUNK + chunk) * 4) = v;
    }
  }
}

// ---------------------- merge 32 chunk-lists + 4-term contraction + relu -> out
// one wave per output row (b,ff); 4 rows per block
__global__ __launch_bounds__(256) void out_kernel(
    const float* __restrict__ cand, const float* __restrict__ R,
    const float* __restrict__ Bb, float* __restrict__ out) {
  const int row = blockIdx.x * 4 + (threadIdx.x >> 6);  // b*512 + ff
  const int lane = threadIdx.x & 63;
  const int b = row >> 9, ff = row & 511;
  const int m2 = ff & 127;

  const float4 cv = *(const float4*)(cand +
      (((size_t)(b * FDIM + ff)) * NCHUNK + (lane & 31)) * 4);
  float t0 = cv.x, t1 = cv.y, t2 = cv.z, t3 = cv.w;
#pragma unroll
  for (int off = 1; off < 32; off <<= 1) {
    float e0 = __shfl_xor(t0, off), e1 = __shfl_xor(t1, off);
    float e2 = __shfl_xor(t2, off), e3 = __shfl_xor(t3, off);
    merge4(t0, t1, t2, t3, e0, e1, e2, e3);
  }
  t0 = fmaxf(t0, 0.f); t1 = fmaxf(t1, 0.f); t2 = fmaxf(t2, 0.f); t3 = fmaxf(t3, 0.f);

  const float* R0 = R + (size_t)(4 * m2) * FDIM;
  const float* Bbr = Bb + (size_t)m2 * FDIM;
  float* ob = out + (size_t)row * FDIM;
#pragma unroll
  for (int jq = 0; jq < 8; ++jq) {
    const int q = jq * 64 + lane;
    float s = Bbr[q];
    s = fmaf(t0, R0[q], s);
    s = fmaf(t1, R0[FDIM + q], s);
    s = fmaf(t2, R0[2 * FDIM + q], s);
    s = fmaf(t3, R0[3 * FDIM + q], s);
    ob[q] = s > 0.f ? s : 0.f;
  }
}

// ---------------------------------------------------------------------------------
extern "C" void kernel_launch(void* const* d_in, const int* in_sizes, int n_in,
                              void* d_out, int out_size, void* d_ws, size_t ws_size,
                              hipStream_t stream) {
  const float* x  = (const float*)d_in[0];
  const float* Wu = (const float*)d_in[1];
  const float* P  = (const float*)d_in[2];
  const float* Q  = (const float*)d_in[3];
  const float* Bb = (const float*)d_in[4];
  float* out = (float*)d_out;

  char* ws = (char*)d_ws;
  unsigned short* xb  = (unsigned short*)(ws);               // 134217728 B
  unsigned short* wuT = (unsigned short*)(ws + 134217728L);  //    524288 B
  float*          R   = (float*)(ws + 134742016L);           //   1048576 B
  float*          cand= (float*)(ws + 135790592L);           //  33554432 B

  hipLaunchKernelGGL(cvt_x_kernel, dim3(2048), dim3(256), 0, stream, x, xb);
  hipLaunchKernelGGL(cvt_wuT_kernel, dim3(512), dim3(256), 0, stream, Wu, wuT);
  hipLaunchKernelGGL(compute_R_kernel, dim3(2, 512), dim3(256), 0, stream, P, Q, R);
  hipLaunchKernelGGL(gemm_topk_kernel, dim3(1024), dim3(512), 0, stream, xb, wuT, cand);
  hipLaunchKernelGGL(out_kernel, dim3(BSZ * FDIM / 4), dim3(256), 0, stream, cand, R, Bb, out);
}

// Round 4
// 148.615 us; speedup vs baseline: 2.7826x; 1.2143x over previous
//
#include <hip/hip_runtime.h>

// Problem constants
#define BSZ   32
#define SEQ   4096
#define FDIM  512
#define KTOP  4
#define FK    128                 // FDIM / KTOP
#define MTOT  (BSZ * SEQ)         // 131072 GEMM rows
#define NCHUNK 32                 // 4096 / 128 seq-chunks per batch

// 256x256 GEMM tile geometry
#define BM2  256
#define BN2  256
#define BK2  64
#define NKT  (FDIM / BK2)         // 8 K-tiles

typedef __attribute__((ext_vector_type(8))) short bf16x8;
typedef __attribute__((ext_vector_type(4))) float f32x4;
typedef __attribute__((ext_vector_type(8))) unsigned short u16x8;

typedef __attribute__((address_space(1))) void void_g;
typedef __attribute__((address_space(3))) void void_l;

static __device__ __forceinline__ void load_lds16(const void* g, void* l) {
  __builtin_amdgcn_global_load_lds((void_g*)g, (void_l*)l, 16, 0, 0);
}

static __device__ __forceinline__ unsigned short f2bf(float f) {
  unsigned int u = __float_as_uint(f);
  unsigned int r = (u + 0x7fffu + ((u >> 16) & 1u)) >> 16;  // RNE
  return (unsigned short)r;
}

// ---- sorting-network helpers (descending) ----
static __device__ __forceinline__ void sort2(float& a, float& b) {
  float mx = fmaxf(a, b), mn = fminf(a, b); a = mx; b = mn;
}
static __device__ __forceinline__ void sort4(float& a, float& b, float& c, float& d) {
  sort2(a, b); sort2(c, d); sort2(a, c); sort2(b, d); sort2(b, c);
}
// merge two descending sorted-4 lists, keep top-4 descending in a..d
static __device__ __forceinline__ void merge4(float& a, float& b, float& c, float& d,
                                              float e, float f, float g, float h) {
  float m0 = fmaxf(a, h), m1 = fmaxf(b, g), m2 = fmaxf(c, f), m3 = fmaxf(d, e);
  sort2(m0, m2); sort2(m1, m3); sort2(m0, m1); sort2(m2, m3);
  a = m0; b = m1; c = m2; d = m3;
}

// ------------------------------------------------- Wu [k][n] f32 -> WuT [n][k] bf16
__global__ __launch_bounds__(256) void cvt_wuT_kernel(const float* __restrict__ Wu,
                                                      unsigned short* __restrict__ WuT) {
  int nn = blockIdx.x;  // 0..511
  for (int k = threadIdx.x; k < FDIM; k += blockDim.x)
    WuT[(size_t)nn * FDIM + k] = f2bf(Wu[(size_t)k * FDIM + nn]);
}

// ------------------------------------------------------------------- R precompute
// R[g][q] = sum_m P2[g][m] * Q[(g%4)*128 + m][q],  P2 = P.reshape(512,128)
__global__ __launch_bounds__(256) void compute_R_kernel(const float* __restrict__ P,
                                                        const float* __restrict__ Q,
                                                        float* __restrict__ R) {
  int g = blockIdx.y;                        // 0..511
  int q = blockIdx.x * 256 + threadIdx.x;    // 0..511
  __shared__ float p2[FK];
  if (threadIdx.x < FK) p2[threadIdx.x] = P[(size_t)g * FK + threadIdx.x];
  __syncthreads();
  const float* Qb = Q + (size_t)((g & 3) * FK) * FDIM + q;
  float s = 0.f;
#pragma unroll 8
  for (int m = 0; m < FK; ++m) s = fmaf(p2[m], Qb[(size_t)m * FDIM], s);
  R[(size_t)g * FDIM + q] = s;
}

// ------- 256x256 pipelined GEMM (A = f32 x, converted in-flight) + fused top-4
// X [MTOT][512] f32, Bt [n][k] bf16. Output: cand[b][f][chunk][4] f32 (sorted desc)
// 8 waves (2M x 4N). A: reg-staged (global f32 -> cvt -> swizzled ds_write).
// B: gload_lds with inverse-swizzled global source. Double-buffered LDS.
__global__ __launch_bounds__(512, 2) void gemm_topk_kernel(
    const float* __restrict__ X, const unsigned short* __restrict__ Bt,
    float* __restrict__ cand) {
  __shared__ __align__(16) unsigned short As[2][BM2 * BK2];  // 2 x 32 KB
  __shared__ __align__(16) unsigned short Bs[2][BM2 * BK2];  // 2 x 32 KB

  const int tid = threadIdx.x;
  const int lane = tid & 63;
  const int w = tid >> 6;                 // 0..7
  const int wm = w & 1, wn = w >> 1;      // 2 x 4 wave grid

  // XCD-grouped mapping: both n-tiles of one m-tile land adjacent on one XCD.
  const int xcd = blockIdx.x & 7;
  const int jj = blockIdx.x >> 3;         // 0..127
  const int t = xcd * 128 + jj;           // 0..1023
  const int mtile = t >> 1, ntile = t & 1;
  const int m0 = mtile * BM2, n0 = ntile * BN2;

  // ---- A staging (f32 source, reg roundtrip, swizzled ds_write) ----
  // slot s = i*512 + tid: row = i*64 + (tid>>3), 16B-slot sc = tid&7
  const int arow = tid >> 3;
  const int asc = tid & 7;
  const int aswz = (arow & 7) << 4;       // row&7 independent of i (i*64 ≡ 0 mod 8)
  const float* axp[4];
  int aldst[4];
#pragma unroll
  for (int i = 0; i < 4; ++i) {
    const int row = i * 64 + arow;
    axp[i] = X + (size_t)(m0 + row) * FDIM + asc * 8;
    aldst[i] = row * 128 + ((asc * 16) ^ aswz);
  }
  float4 ar[4][2];

#define ALOAD(kt)                                                              \
  {                                                                            \
    _Pragma("unroll") for (int i = 0; i < 4; ++i) {                            \
      const float4* p = (const float4*)(axp[i] + (kt) * BK2);                  \
      ar[i][0] = p[0];                                                         \
      ar[i][1] = p[1];                                                         \
    }                                                                          \
  }

#define AWRITE(buf)                                                            \
  {                                                                            \
    _Pragma("unroll") for (int i = 0; i < 4; ++i) {                            \
      u16x8 o;                                                                 \
      o[0] = f2bf(ar[i][0].x); o[1] = f2bf(ar[i][0].y);                        \
      o[2] = f2bf(ar[i][0].z); o[3] = f2bf(ar[i][0].w);                        \
      o[4] = f2bf(ar[i][1].x); o[5] = f2bf(ar[i][1].y);                        \
      o[6] = f2bf(ar[i][1].z); o[7] = f2bf(ar[i][1].w);                        \
      *(u16x8*)((char*)As[buf] + aldst[i]) = o;                                \
    }                                                                          \
  }

  // ---- B staging: gload_lds, linear dest + inverse-swizzled source ----
  const char* bsrc[4];
#pragma unroll
  for (int i = 0; i < 4; ++i) {
    int o = i * 8192 + tid * 16;
    int row = o >> 7;
    int colb = (o & 127) ^ ((row & 7) << 4);
    bsrc[i] = (const char*)(Bt + (size_t)(n0 + row) * FDIM) + colb;
  }
  const int ldst = (tid >> 6) * 512;      // shorts; wave-uniform base

#define STAGE_B(kt, buf)                                                       \
  {                                                                            \
    _Pragma("unroll") for (int i = 0; i < 4; ++i)                              \
        load_lds16(bsrc[i] + (kt) * 128, (void*)(&Bs[buf][i * 4096 + ldst]));  \
  }

  // ---- fragment read offsets (swizzled) ----
  const int lr = lane & 15;
  const int g16 = lane >> 4;              // 0..3
  const int swz = (lr & 7) << 4;
  const int arow0 = (wm * 128 + lr) * 128;
  const int brow0 = (wn * 64 + lr) * 128;

  f32x4 acc[8][4];
#pragma unroll
  for (int mi = 0; mi < 8; ++mi)
#pragma unroll
    for (int ni = 0; ni < 4; ++ni) acc[mi][ni] = {0.f, 0.f, 0.f, 0.f};

  // prologue: stage tile 0
  STAGE_B(0, 0);
  ALOAD(0);
  AWRITE(0);            // compiler inserts vmcnt wait for ar
  __syncthreads();      // drains vmcnt (B gloads) + lgkm (A writes)

  for (int kt = 0; kt < NKT; ++kt) {
    const int cur = kt & 1;
    if (kt + 1 < NKT) {
      STAGE_B(kt + 1, cur ^ 1);
      ALOAD(kt + 1);
    }
    const char* Ab = (const char*)As[cur];
    const char* Bb = (const char*)Bs[cur];
#pragma unroll
    for (int kk = 0; kk < 2; ++kk) {
      bf16x8 af[8], bfr[4];
      const int kcol = kk * 64;
#pragma unroll
      for (int mi = 0; mi < 8; ++mi)
        af[mi] = *(const bf16x8*)(Ab + arow0 + mi * 2048 + ((kcol + g16 * 16) ^ swz));
#pragma unroll
      for (int ni = 0; ni < 4; ++ni)
        bfr[ni] = *(const bf16x8*)(Bb + brow0 + ni * 2048 + ((kcol + g16 * 16) ^ swz));
      __builtin_amdgcn_s_setprio(1);
#pragma unroll
      for (int mi = 0; mi < 8; ++mi)
#pragma unroll
        for (int ni = 0; ni < 4; ++ni)
          acc[mi][ni] = __builtin_amdgcn_mfma_f32_16x16x32_bf16(af[mi], bfr[ni],
                                                                acc[mi][ni], 0, 0, 0);
      __builtin_amdgcn_s_setprio(0);
    }
    if (kt + 1 < NKT) {
      AWRITE(cur ^ 1);   // waits on ar's global loads (vmcnt) implicitly
      __syncthreads();   // drains vmcnt+lgkm; buf[cur^1] ready, buf[cur] free
    }
  }

  // ---- fused top-4: each wave owns one 128-row chunk (wm), cols wn*64..+63 ----
  const int mchunk = mtile * 2 + wm;      // global 128-row chunk id
  const int b = mchunk >> 5;
  const int chunk = mchunk & 31;
#pragma unroll
  for (int ni = 0; ni < 4; ++ni) {
    float a0 = acc[0][ni][0], a1 = acc[0][ni][1], a2 = acc[0][ni][2], a3 = acc[0][ni][3];
    sort4(a0, a1, a2, a3);
#pragma unroll
    for (int mi = 1; mi < 8; ++mi) {
      float b0 = acc[mi][ni][0], b1 = acc[mi][ni][1];
      float b2 = acc[mi][ni][2], b3 = acc[mi][ni][3];
      sort4(b0, b1, b2, b3);
      merge4(a0, a1, a2, a3, b0, b1, b2, b3);
    }
#pragma unroll
    for (int off = 16; off < 64; off <<= 1) {
      float e0 = __shfl_xor(a0, off), e1 = __shfl_xor(a1, off);
      float e2 = __shfl_xor(a2, off), e3 = __shfl_xor(a3, off);
      merge4(a0, a1, a2, a3, e0, e1, e2, e3);
    }
    if (lane < 16) {
      const int f = n0 + wn * 64 + ni * 16 + lane;
      float4 v; v.x = a0; v.y = a1; v.z = a2; v.w = a3;
      *(float4*)(cand + (((size_t)(b * FDIM + f)) * NCHUNK + chunk) * 4) = v;
    }
  }
}

// ---------------------- merge 32 chunk-lists + 4-term contraction + relu -> out
// one wave per output row (b,ff); 4 rows per block
__global__ __launch_bounds__(256) void out_kernel(
    const float* __restrict__ cand, const float* __restrict__ R,
    const float* __restrict__ Bb, float* __restrict__ out) {
  const int row = blockIdx.x * 4 + (threadIdx.x >> 6);  // b*512 + ff
  const int lane = threadIdx.x & 63;
  const int b = row >> 9, ff = row & 511;
  const int m2 = ff & 127;

  const float4 cv = *(const float4*)(cand +
      (((size_t)(b * FDIM + ff)) * NCHUNK + (lane & 31)) * 4);
  float t0 = cv.x, t1 = cv.y, t2 = cv.z, t3 = cv.w;
#pragma unroll
  for (int off = 1; off < 32; off <<= 1) {
    float e0 = __shfl_xor(t0, off), e1 = __shfl_xor(t1, off);
    float e2 = __shfl_xor(t2, off), e3 = __shfl_xor(t3, off);
    merge4(t0, t1, t2, t3, e0, e1, e2, e3);
  }
  t0 = fmaxf(t0, 0.f); t1 = fmaxf(t1, 0.f); t2 = fmaxf(t2, 0.f); t3 = fmaxf(t3, 0.f);

  const float* R0 = R + (size_t)(4 * m2) * FDIM;
  const float* Bbr = Bb + (size_t)m2 * FDIM;
  float* ob = out + (size_t)row * FDIM;
#pragma unroll
  for (int jq = 0; jq < 8; ++jq) {
    const int q = jq * 64 + lane;
    float s = Bbr[q];
    s = fmaf(t0, R0[q], s);
    s = fmaf(t1, R0[FDIM + q], s);
    s = fmaf(t2, R0[2 * FDIM + q], s);
    s = fmaf(t3, R0[3 * FDIM + q], s);
    ob[q] = s > 0.f ? s : 0.f;
  }
}

// ---------------------------------------------------------------------------------
extern "C" void kernel_launch(void* const* d_in, const int* in_sizes, int n_in,
                              void* d_out, int out_size, void* d_ws, size_t ws_size,
                              hipStream_t stream) {
  const float* x  = (const float*)d_in[0];
  const float* Wu = (const float*)d_in[1];
  const float* P  = (const float*)d_in[2];
  const float* Q  = (const float*)d_in[3];
  const float* Bb = (const float*)d_in[4];
  float* out = (float*)d_out;

  char* ws = (char*)d_ws;
  unsigned short* wuT = (unsigned short*)(ws);          //  524288 B
  float*          R   = (float*)(ws + 524288L);         // 1048576 B
  float*          cand= (float*)(ws + 1572864L);        // 8388608 B

  hipLaunchKernelGGL(cvt_wuT_kernel, dim3(512), dim3(256), 0, stream, Wu, wuT);
  hipLaunchKernelGGL(compute_R_kernel, dim3(2, 512), dim3(256), 0, stream, P, Q, R);
  hipLaunchKernelGGL(gemm_topk_kernel, dim3(1024), dim3(512), 0, stream, x, wuT, cand);
  hipLaunchKernelGGL(out_kernel, dim3(BSZ * FDIM / 4), dim3(256), 0, stream, cand, R, Bb, out);
}